// Round 2
// baseline (492.146 us; speedup 1.0000x reference)
//
#include <hip/hip_runtime.h>

typedef _Float16 f16;
typedef __attribute__((ext_vector_type(8))) _Float16 half8;
typedef __attribute__((ext_vector_type(4))) float floatx4;

#define BB    16
#define TSN   16
#define NNP   4096
#define HID   64
#define KPK   224     // 6 k-tiles of 32 (h taps) + 1 k-tile (x taps + bias)
#define WOUT  128     // valid output positions per block
#define HALO  8       // time-halo per 8-step chunk (2 launches)
#define WCMP  144     // computed rows per step = WOUT + 2*HALO (9 m-tiles)
#define HROWS 146     // h-buffer rows = WCMP + 2 (conv halo)
#define NMS   9
#define NTIL  32

#define LOG2E 1.44269504088896340736f

// LDS h layout: row stride 64 f16 (128 B == 0 mod 32 banks), 16B chunk
// XOR-swizzled by row (phys_chunk = chunk ^ (row&7)) -> b128 reads balanced,
// dword epilogue writes conflict-light. [verified R5: conflicts 8.3M -> 229K]
__device__ __forceinline__ int hadr(int rr, int c) {   // f16 index
    return rr * 64 + ((c ^ (rr & 7)) << 3);
}
__device__ __forceinline__ unsigned f16pair(float a, float b) {
    union { f16 h; unsigned short u; } ua, ub;
    ua.h = (f16)a; ub.h = (f16)b;
    return (unsigned)ua.u | ((unsigned)ub.u << 16);
}
// one-instruction f32x2 -> f16x2 pack (v_cvt_pkrtz_f16_f32).
// NOTE: builtin returns __fp16-vector, not _Float16-vector (R14 compile fix).
__device__ __forceinline__ unsigned pkrtz(float a, float b) {
    typedef __fp16 h2v __attribute__((ext_vector_type(2)));
    h2v r = __builtin_amdgcn_cvt_pkrtz(a, b);
    union { h2v h; unsigned u; } cv; cv.h = r; return cv.u;
}

// Raw-rate transcendentals (no -ffast-math in harness). ~1 ulp each.
__device__ __forceinline__ float fast_exp2(float x) {
#if __has_builtin(__builtin_amdgcn_exp2f)
    return __builtin_amdgcn_exp2f(x);
#else
    return exp2f(x);
#endif
}
__device__ __forceinline__ float fast_rcp(float x) {
#if __has_builtin(__builtin_amdgcn_rcpf)
    return __builtin_amdgcn_rcpf(x);
#else
    return 1.0f / x;
#endif
}

// Lane exchanges via DPP (VALU) instead of ds_swizzle (DS pipe).
__device__ __forceinline__ float dpp_xor8(float v) {
    return __int_as_float(__builtin_amdgcn_mov_dpp(__float_as_int(v), 0x128, 0xF, 0xF, true));
}
__device__ __forceinline__ float dpp_xor1(float v) {
    return __int_as_float(__builtin_amdgcn_mov_dpp(__float_as_int(v), 0xB1, 0xF, 0xF, true));
}

// ---------------------------------------------------------------------------
// Pack conv_w (OIHW 256x65x3x3, only kw=1 live) -> f16 wpack[oc][k]:
//   k = kt*32+c;  kt<6: tap=kt>>1, ch j=(kt&1)*32+c;  kt=6: c<3 -> x tap c,
//   c==3 -> bias (paired with constant 1.0 in the x k-slot; R15).
// Gate pre-scale folded in: i/f/o by -log2e, g by 2*log2e.
// ---------------------------------------------------------------------------
__global__ void pack_w_kernel(const float* __restrict__ conv_w,
                              const float* __restrict__ conv_b,
                              f16* __restrict__ wpack) {
    int idx = blockIdx.x * 256 + threadIdx.x;
    if (idx >= 4 * 64 * KPK) return;
    int k  = idx % KPK;
    int oc = idx / KPK;
    int kt = k >> 5, c = k & 31;
    float w = 0.0f;
    if (kt < 6) {
        int tap = kt >> 1;
        int j   = (kt & 1) * 32 + c;
        w = conv_w[((oc * 65 + 1 + j) * 3 + tap) * 3 + 1];
    } else if (c < 3) {
        w = conv_w[((oc * 65 + 0) * 3 + c) * 3 + 1];
    } else if (c == 3) {
        w = conv_b[oc];                       // bias folded into MFMA (R15)
    }
    float scale = (oc >= 192) ? (2.0f * LOG2E) : (-LOG2E);
    wpack[oc * KPK + k] = (f16)(w * scale);
}

// ---------------------------------------------------------------------------
// R16: MFMA split into barrier-independent x-part (reads only the step's
// pre-staged xt, seeds from zacc) and the h-part (reads the barrier-protected
// h buffer). The x-part of the first two tiles issues BEFORE __syncthreads,
// converting barrier-wait into matrix work.
// ---------------------------------------------------------------------------
template <int MS>
__device__ __forceinline__ void do_mfx(
    const f16* __restrict__ xts, const half8 (&bf)[7][2],
    const floatx4& zacc, floatx4 (&acc)[2], int m)
{
    const int ar = MS * 16 + m;
    half8 a = *(const half8*)(xts + ar * 8);
    acc[0] = __builtin_amdgcn_mfma_f32_16x16x32_f16(a, bf[6][0], zacc, 0, 0, 0);
    acc[1] = __builtin_amdgcn_mfma_f32_16x16x32_f16(a, bf[6][1], zacc, 0, 0, 0);
}

// h-part: 12 MFMA cluster wrapped in s_setprio(1) (T5) — our ping-pong
// schedule gives waves role diversity (MF vs EP phase), so the SIMD arbiter
// can keep the matrix pipe fed from MF-phase waves.
template <int MS>
__device__ __forceinline__ void do_mfh(
    const f16* __restrict__ hrd, const half8 (&bf)[7][2],
    floatx4 (&acc)[2], int m, int kg)
{
    const int ar = MS * 16 + m;
    __builtin_amdgcn_s_setprio(1);
#pragma unroll
    for (int kt = 0; kt < 6; ++kt) {
        half8 a = *(const half8*)(hrd + hadr(ar + (kt >> 1), (kt & 1) * 4 + kg));
        acc[0] = __builtin_amdgcn_mfma_f32_16x16x32_f16(a, bf[kt][0], acc[0], 0, 0, 0);
        acc[1] = __builtin_amdgcn_mfma_f32_16x16x32_f16(a, bf[kt][1], acc[1], 0, 0, 0);
    }
    __builtin_amdgcn_s_setprio(0);
}

// ---------------------------------------------------------------------------
// Single-tile epilogue: gate exchange (DPP), LSTM pointwise, h write.
// R15: rcp-fusion — 7 trans ops per element.
// R16: batched trans — all 8 independent v_exp (both j elements) issue before
// the dependent algebra, filling the trans pipe without dep-stall gaps.
// ---------------------------------------------------------------------------
template <int MS>
__device__ __forceinline__ void do_epi(
    f16* __restrict__ hwr, floatx4 (&acc)[2], float (&creg)[NMS * 2],
    int m, int kg, int wave, bool lowm, bool edge, int n0)
{
    float pg[2][2];
#pragma unroll
    for (int q = 0; q < 2; ++q)
#pragma unroll
        for (int j = 0; j < 2; ++j) {
            float send = lowm ? acc[q][2 + j] : acc[q][j];
            pg[q][j] = dpp_xor8(send);
        }

    // gate pre-activations, both elements: [j][i,f,o,g]
    float Y[2][4];
#pragma unroll
    for (int j = 0; j < 2; ++j) {
        Y[j][0] = lowm ? acc[0][j] : pg[0][j];
        Y[j][1] = lowm ? pg[0][j] : acc[0][2 + j];
        Y[j][2] = lowm ? acc[1][j] : pg[1][j];
        Y[j][3] = lowm ? pg[1][j] : acc[1][2 + j];
    }
    // 8 independent exps back-to-back (trans pipe fill)
    float E[2][4];
#pragma unroll
    for (int j = 0; j < 2; ++j)
#pragma unroll
        for (int g = 0; g < 4; ++g) E[j][g] = fast_exp2(Y[j][g]);

#pragma unroll
    for (int j = 0; j < 2; ++j) {
        int r  = lowm ? j : 2 + j;
        float Fi = 1.0f + E[j][0], Ff = 1.0f + E[j][1];
        float Fo = 1.0f + E[j][2], Fg = 1.0f + E[j][3];
        const int ridx = MS * 2 + j;
        float P  = Fi * Fg;
        float N  = fmaf(E[j][3] - 1.0f, Ff, creg[ridx] * P);
        float cn = N * fast_rcp(P * Ff);          // sig(f)*c + sig(i)*tanh(g)
        float Ec = fast_exp2(cn * (2.0f * LOG2E));
        float hnf = (Ec - 1.0f) * fast_rcp(Fo * (1.0f + Ec));  // sig(o)*tanh(cn)
        creg[ridx] = cn;
        int rit = MS * 16 + kg * 4 + r;        // compute-window row
        if (edge) {
            int pos = n0 - HALO + rit;
            if (pos < 0 || pos >= NNP) hnf = 0.0f;  // zero-pad semantics
        }
        float po = dpp_xor1(hnf);               // partner hid^1
        if (!(m & 1)) {                          // even lane packs dword
            int rr = rit + 1;
            ((unsigned*)hwr)[rr * 32 + ((wave ^ (rr & 7)) << 2) + ((m & 7) >> 1)] =
                pkrtz(hnf, po);
        }
    }
}

// ---------------------------------------------------------------------------
// ConvLSTM 8-step chunk, 512 independent blocks, NO inter-block sync.
// Block = 512 thr (8 waves). Gate-packed MFMA N-dim (R9); DPP exchange (R13);
// all 8 x-steps pre-staged, ONE barrier/step (R12); halo-8 recompute (R9).
// R14: software pipeline (ping-pong acc, wave-group stagger 0/4).
// R15: rcp-fusion (7 trans/element), bias in spare x k-slot, zacc seed.
// R16: latency attack — (a) s_setprio(1) around h-MFMA cluster (T5),
// (b) pre-barrier x-MFMA hoist for the first two tiles (barrier-independent
// work fills the sync wait), (c) batched trans in epilogue,
// (d) __launch_bounds__(512,4) guards the 128-VGPR occupancy cliff.
// ---------------------------------------------------------------------------
__global__ __launch_bounds__(512, 4)
void lstm_kernel(const float* __restrict__ x, const f16* __restrict__ wpack,
                 f16* __restrict__ h_glob, float* __restrict__ c_glob, int phase)
{
    __shared__ __align__(16) f16 hlds[2][HROWS * 64];
    __shared__ __align__(16) f16 xt[8 * WCMP * 8];

    const int blk  = blockIdx.x;
    const int b    = blk >> 5;
    const int tau  = blk & 31;
    const int n0   = tau * WOUT;
    const int tid  = threadIdx.x;
    const int lane = tid & 63;
    const int wave = tid >> 6;             // 0..7
    const int m    = lane & 15;
    const int kg   = lane >> 4;
    const int gh   = m >> 3;               // gate half of this lane's column
    const int hid  = wave * 8 + (m & 7);
    const bool lowm = (m < 8);
    const bool edge = (tau == 0) || (tau == NTIL - 1);
    const int s0   = phase * 8;

    // B fragments, gate-packed: 14 half8 = 56 VGPR, resident all 8 steps.
    half8 bf[7][2];
#pragma unroll
    for (int kt = 0; kt < 7; ++kt)
#pragma unroll
        for (int q = 0; q < 2; ++q)
            bf[kt][q] = *(const half8*)(wpack + (size_t)((q * 2 + gh) * 64 + hid) * KPK + kt * 32 + kg * 8);

    const floatx4 zacc = {0.0f, 0.0f, 0.0f, 0.0f};   // persistent MFMA C seed

    float creg[NMS * 2];

    // ---- one-time staging: all 8 steps of x (slot3 = 1.0 pairs with bias) ----
    for (int i = tid; i < 8 * WCMP; i += 512) {
        int ss = i / WCMP, r = i - ss * WCMP;
        const float* xb = x + ((size_t)b * TSN + s0 + ss) * NNP;
        int p = n0 - HALO + r;
        float v0 = (p - 1 >= 0 && p - 1 < NNP) ? xb[p - 1] : 0.0f;
        float v1 = (p >= 0 && p < NNP) ? xb[p] : 0.0f;
        float v2 = (p + 1 >= 0 && p + 1 < NNP) ? xb[p + 1] : 0.0f;
        unsigned* q = (unsigned*)(xt + (size_t)i * 8);
        q[0] = f16pair(v0, v1);
        q[1] = f16pair(v2, 1.0f);
        q[2] = 0u; q[3] = 0u;
    }

    if (phase == 0) {
#pragma unroll
        for (int i = 0; i < NMS * 2; ++i) creg[i] = 0.0f;
        for (int i = tid; i < HROWS * 64; i += 512) { hlds[0][i] = (f16)0; hlds[1][i] = (f16)0; }
    } else {
        // seed h(8) window from global (rr <-> pos n0-HALO-1+rr), OOB -> 0
        for (int i = tid; i < HROWS * 8; i += 512) {
            int rr = i >> 3, c = i & 7;
            int pos = n0 - HALO - 1 + rr;
            half8 v = {};
            if (pos >= 0 && pos < NNP)
                v = *(const half8*)(h_glob + ((size_t)b * NNP + pos) * HID + c * 8);
            *(half8*)(hlds[0] + hadr(rr, c)) = v;
        }
        // hlds[1]: only halo rows 0 / HROWS-1 are read before being written
        for (int i = tid; i < 2 * 64; i += 512) {
            int rr = (i >= 64) ? (HROWS - 1) : 0;
            hlds[1][rr * 64 + (i & 63)] = (f16)0;
        }
#pragma unroll
        for (int ms = 0; ms < NMS; ++ms)
#pragma unroll
            for (int j = 0; j < 2; ++j) {
                int r   = lowm ? j : 2 + j;
                int pos = n0 - HALO + ms * 16 + kg * 4 + r;
                creg[ms * 2 + j] = (pos >= 0 && pos < NNP)
                    ? c_glob[((size_t)b * NNP + pos) * HID + hid] : 0.0f;
            }
    }

    __syncthreads();   // staging/seed writes vs first pre-barrier xt reads

#pragma unroll 1
    for (int s = s0; s < s0 + 8; ++s) {
        const f16* hrd = hlds[s & 1];
        f16*       hwr = hlds[(s & 1) ^ 1];
        const f16* xts = xt + (size_t)(s - s0) * WCMP * 8;

        floatx4 accA[2], accB[2];
#define MFX(MS, A) do_mfx<MS>(xts, bf, zacc, A, m)
#define MFH(MS, A) do_mfh<MS>(hrd, bf, A, m, kg)
#define MFF(MS, A) do { MFX(MS, A); MFH(MS, A); } while (0)
#define EP(MS, A)  do_epi<MS>(hwr, A, creg, m, kg, wave, lowm, edge, n0)
        // pre-barrier: x-part of the first two tiles (reads only xt, which is
        // written once before the loop — barrier-independent work)
        if (wave < 4) { MFX(0, accA); MFX(1, accB); }
        else          { MFX(4, accA); MFX(5, accB); }

        __syncthreads();   // step s's h reads vs step s-1's h writes

        if (wave < 4) {
            MFH(0, accA);
            MFH(1, accB); EP(0, accA);
            MFF(2, accA); EP(1, accB);
            MFF(3, accB); EP(2, accA);
            MFF(4, accA); EP(3, accB);
            MFF(5, accB); EP(4, accA);
            MFF(6, accA); EP(5, accB);
            MFF(7, accB); EP(6, accA);
            MFF(8, accA); EP(7, accB);
            EP(8, accA);
        } else {
            MFH(4, accA);
            MFH(5, accB); EP(4, accA);
            MFF(6, accA); EP(5, accB);
            MFF(7, accB); EP(6, accA);
            MFF(8, accA); EP(7, accB);
            MFF(0, accB); EP(8, accA);
            MFF(1, accA); EP(0, accB);
            MFF(2, accB); EP(1, accA);
            MFF(3, accA); EP(2, accB);
            EP(3, accA);
        }
#undef MFX
#undef MFH
#undef MFF
#undef EP
    }
    __syncthreads();   // last step's hwr (= hlds[0]) complete

    // h(s0+8) is in hlds[0] (last step is odd); valid rows rr = row+HALO+1.
    for (int i = tid; i < WOUT * 8; i += 512) {
        int row = i >> 3, c = i & 7;
        half8 v = *(const half8*)(hlds[0] + hadr(row + HALO + 1, c));
        *(half8*)(h_glob + ((size_t)b * NNP + n0 + row) * HID + c * 8) = v;
    }
    if (phase == 0) {
        // persist c(8) for valid rows
#pragma unroll
        for (int ms = 0; ms < NMS; ++ms)
#pragma unroll
            for (int j = 0; j < 2; ++j) {
                int r   = lowm ? j : 2 + j;
                int rit = ms * 16 + kg * 4 + r;
                int pos = n0 - HALO + rit;
                if (rit >= HALO && rit < HALO + WOUT && pos >= 0 && pos < NNP)
                    c_glob[((size_t)b * NNP + pos) * HID + hid] = creg[ms * 2 + j];
            }
    }
}

// ---------------------------------------------------------------------------
// fc: out[b,t,n] = sum_hid h[b][n][hid]*fc_w[hid] + fc_b, broadcast over t
// ---------------------------------------------------------------------------
__global__ void fc_kernel(const f16* __restrict__ h, const float* __restrict__ fc_w,
                          const float* __restrict__ fc_b, float* __restrict__ out) {
    int idx = blockIdx.x * 256 + threadIdx.x;      // b*NNP + n
    const half8* hp = (const half8*)(h + (size_t)idx * HID);
    float s = 0.0f;
#pragma unroll
    for (int q = 0; q < 8; ++q) {
        half8 v = hp[q];
#pragma unroll
        for (int e = 0; e < 8; ++e) s += (float)v[e] * fc_w[q * 8 + e];
    }
    s += fc_b[0];
    int b = idx >> 12, n = idx & (NNP - 1);
#pragma unroll
    for (int t = 0; t < TSN; ++t) out[((size_t)b * TSN + t) * NNP + n] = s;
}

extern "C" void kernel_launch(void* const* d_in, const int* in_sizes, int n_in,
                              void* d_out, int out_size, void* d_ws, size_t ws_size,
                              hipStream_t stream) {
    const float* x      = (const float*)d_in[0];
    const float* conv_w = (const float*)d_in[1];
    const float* conv_b = (const float*)d_in[2];
    const float* fc_w   = (const float*)d_in[3];
    const float* fc_b   = (const float*)d_in[4];
    float* out = (float*)d_out;

    char* ws = (char*)d_ws;
    const size_t hbytes = (size_t)BB * NNP * HID * sizeof(f16);     // 8.39 MB
    f16*   wpack  = (f16*)ws;                                       // 112 KiB
    f16*   h_glob = (f16*)(ws + 131072);
    float* c_glob = (float*)(ws + 131072 + hbytes);                 // 16.8 MB

    pack_w_kernel<<<(4 * 64 * KPK + 255) / 256, 256, 0, stream>>>(conv_w, conv_b, wpack);
    lstm_kernel<<<BB * NTIL, 512, 0, stream>>>(x, wpack, h_glob, c_glob, 0);
    lstm_kernel<<<BB * NTIL, 512, 0, stream>>>(x, wpack, h_glob, c_glob, 1);
    fc_kernel<<<BB * NNP / 256, 256, 0, stream>>>(h_glob, fc_w, fc_b, out);
}

// Round 3
// 254.582 us; speedup vs baseline: 1.9332x; 1.9332x over previous
//
#include <hip/hip_runtime.h>

typedef _Float16 f16;
typedef __attribute__((ext_vector_type(8))) _Float16 half8;
typedef __attribute__((ext_vector_type(4))) float floatx4;

#define BB    16
#define TSN   16
#define NNP   4096
#define HID   64
#define KPK   224     // 6 k-tiles of 32 (h taps) + 1 k-tile (x taps + bias)
#define WOUT  128     // valid output positions per block
#define HALO  8       // time-halo per 8-step chunk (2 launches)
#define WCMP  144     // computed rows per step = WOUT + 2*HALO (9 m-tiles)
#define HROWS 146     // h-buffer rows = WCMP + 2 (conv halo)
#define NMS   9
#define NTIL  32

#define LOG2E 1.44269504088896340736f

// LDS h layout: row stride 64 f16 (128 B == 0 mod 32 banks), 16B chunk
// XOR-swizzled by row (phys_chunk = chunk ^ (row&7)) -> b128 reads balanced,
// dword epilogue writes conflict-light. [verified R5: conflicts 8.3M -> 229K]
__device__ __forceinline__ int hadr(int rr, int c) {   // f16 index
    return rr * 64 + ((c ^ (rr & 7)) << 3);
}
__device__ __forceinline__ unsigned f16pair(float a, float b) {
    union { f16 h; unsigned short u; } ua, ub;
    ua.h = (f16)a; ub.h = (f16)b;
    return (unsigned)ua.u | ((unsigned)ub.u << 16);
}
// one-instruction f32x2 -> f16x2 pack (v_cvt_pkrtz_f16_f32).
// NOTE: builtin returns __fp16-vector, not _Float16-vector (R14 compile fix).
__device__ __forceinline__ unsigned pkrtz(float a, float b) {
    typedef __fp16 h2v __attribute__((ext_vector_type(2)));
    h2v r = __builtin_amdgcn_cvt_pkrtz(a, b);
    union { h2v h; unsigned u; } cv; cv.h = r; return cv.u;
}

// Raw-rate transcendentals (no -ffast-math in harness). ~1 ulp each.
__device__ __forceinline__ float fast_exp2(float x) {
#if __has_builtin(__builtin_amdgcn_exp2f)
    return __builtin_amdgcn_exp2f(x);
#else
    return exp2f(x);
#endif
}
__device__ __forceinline__ float fast_rcp(float x) {
#if __has_builtin(__builtin_amdgcn_rcpf)
    return __builtin_amdgcn_rcpf(x);
#else
    return 1.0f / x;
#endif
}

// Lane exchanges via DPP (VALU) instead of ds_swizzle (DS pipe).
__device__ __forceinline__ float dpp_xor8(float v) {
    return __int_as_float(__builtin_amdgcn_mov_dpp(__float_as_int(v), 0x128, 0xF, 0xF, true));
}
__device__ __forceinline__ float dpp_xor1(float v) {
    return __int_as_float(__builtin_amdgcn_mov_dpp(__float_as_int(v), 0xB1, 0xF, 0xF, true));
}

// ---------------------------------------------------------------------------
// Pack conv_w (OIHW 256x65x3x3, only kw=1 live) -> f16 wpack[oc][k]:
//   k = kt*32+c;  kt<6: tap=kt>>1, ch j=(kt&1)*32+c;  kt=6: c<3 -> x tap c,
//   c==3 -> bias (paired with constant 1.0 in the x k-slot; R15).
// Gate pre-scale folded in: i/f/o by -log2e, g by 2*log2e.
// ---------------------------------------------------------------------------
__global__ void pack_w_kernel(const float* __restrict__ conv_w,
                              const float* __restrict__ conv_b,
                              f16* __restrict__ wpack) {
    int idx = blockIdx.x * 256 + threadIdx.x;
    if (idx >= 4 * 64 * KPK) return;
    int k  = idx % KPK;
    int oc = idx / KPK;
    int kt = k >> 5, c = k & 31;
    float w = 0.0f;
    if (kt < 6) {
        int tap = kt >> 1;
        int j   = (kt & 1) * 32 + c;
        w = conv_w[((oc * 65 + 1 + j) * 3 + tap) * 3 + 1];
    } else if (c < 3) {
        w = conv_w[((oc * 65 + 0) * 3 + c) * 3 + 1];
    } else if (c == 3) {
        w = conv_b[oc];                       // bias folded into MFMA (R15)
    }
    float scale = (oc >= 192) ? (2.0f * LOG2E) : (-LOG2E);
    wpack[oc * KPK + k] = (f16)(w * scale);
}

// ---------------------------------------------------------------------------
// R16: MFMA split into barrier-independent x-part (reads only the step's
// pre-staged xt, seeds from zacc) and the h-part (reads the barrier-protected
// h buffer). The x-part of the first two tiles issues BEFORE __syncthreads,
// converting barrier-wait into matrix work.
// ---------------------------------------------------------------------------
template <int MS>
__device__ __forceinline__ void do_mfx(
    const f16* __restrict__ xts, const half8 (&bf)[7][2],
    const floatx4& zacc, floatx4 (&acc)[2], int m)
{
    const int ar = MS * 16 + m;
    half8 a = *(const half8*)(xts + ar * 8);
    acc[0] = __builtin_amdgcn_mfma_f32_16x16x32_f16(a, bf[6][0], zacc, 0, 0, 0);
    acc[1] = __builtin_amdgcn_mfma_f32_16x16x32_f16(a, bf[6][1], zacc, 0, 0, 0);
}

// h-part: 12 MFMA cluster wrapped in s_setprio(1) (T5) — our ping-pong
// schedule gives waves role diversity (MF vs EP phase), so the SIMD arbiter
// can keep the matrix pipe fed from MF-phase waves.
template <int MS>
__device__ __forceinline__ void do_mfh(
    const f16* __restrict__ hrd, const half8 (&bf)[7][2],
    floatx4 (&acc)[2], int m, int kg)
{
    const int ar = MS * 16 + m;
    __builtin_amdgcn_s_setprio(1);
#pragma unroll
    for (int kt = 0; kt < 6; ++kt) {
        half8 a = *(const half8*)(hrd + hadr(ar + (kt >> 1), (kt & 1) * 4 + kg));
        acc[0] = __builtin_amdgcn_mfma_f32_16x16x32_f16(a, bf[kt][0], acc[0], 0, 0, 0);
        acc[1] = __builtin_amdgcn_mfma_f32_16x16x32_f16(a, bf[kt][1], acc[1], 0, 0, 0);
    }
    __builtin_amdgcn_s_setprio(0);
}

// ---------------------------------------------------------------------------
// Single-tile epilogue: gate exchange (DPP), LSTM pointwise, h write.
// R15: rcp-fusion — 7 trans ops per element.
// R16: batched trans — all 8 independent v_exp (both j elements) issue before
// the dependent algebra, filling the trans pipe without dep-stall gaps.
// ---------------------------------------------------------------------------
template <int MS>
__device__ __forceinline__ void do_epi(
    f16* __restrict__ hwr, floatx4 (&acc)[2], float (&creg)[NMS * 2],
    int m, int kg, int wave, bool lowm, bool edge, int n0)
{
    float pg[2][2];
#pragma unroll
    for (int q = 0; q < 2; ++q)
#pragma unroll
        for (int j = 0; j < 2; ++j) {
            float send = lowm ? acc[q][2 + j] : acc[q][j];
            pg[q][j] = dpp_xor8(send);
        }

    // gate pre-activations, both elements: [j][i,f,o,g]
    float Y[2][4];
#pragma unroll
    for (int j = 0; j < 2; ++j) {
        Y[j][0] = lowm ? acc[0][j] : pg[0][j];
        Y[j][1] = lowm ? pg[0][j] : acc[0][2 + j];
        Y[j][2] = lowm ? acc[1][j] : pg[1][j];
        Y[j][3] = lowm ? pg[1][j] : acc[1][2 + j];
    }
    // 8 independent exps back-to-back (trans pipe fill)
    float E[2][4];
#pragma unroll
    for (int j = 0; j < 2; ++j)
#pragma unroll
        for (int g = 0; g < 4; ++g) E[j][g] = fast_exp2(Y[j][g]);

#pragma unroll
    for (int j = 0; j < 2; ++j) {
        int r  = lowm ? j : 2 + j;
        float Fi = 1.0f + E[j][0], Ff = 1.0f + E[j][1];
        float Fo = 1.0f + E[j][2], Fg = 1.0f + E[j][3];
        const int ridx = MS * 2 + j;
        float P  = Fi * Fg;
        float N  = fmaf(E[j][3] - 1.0f, Ff, creg[ridx] * P);
        float cn = N * fast_rcp(P * Ff);          // sig(f)*c + sig(i)*tanh(g)
        float Ec = fast_exp2(cn * (2.0f * LOG2E));
        float hnf = (Ec - 1.0f) * fast_rcp(Fo * (1.0f + Ec));  // sig(o)*tanh(cn)
        creg[ridx] = cn;
        int rit = MS * 16 + kg * 4 + r;        // compute-window row
        if (edge) {
            int pos = n0 - HALO + rit;
            if (pos < 0 || pos >= NNP) hnf = 0.0f;  // zero-pad semantics
        }
        float po = dpp_xor1(hnf);               // partner hid^1
        if (!(m & 1)) {                          // even lane packs dword
            int rr = rit + 1;
            ((unsigned*)hwr)[rr * 32 + ((wave ^ (rr & 7)) << 2) + ((m & 7) >> 1)] =
                pkrtz(hnf, po);
        }
    }
}

// ---------------------------------------------------------------------------
// ConvLSTM 8-step chunk, 512 independent blocks, NO inter-block sync.
// Block = 512 thr (8 waves). Gate-packed MFMA N-dim (R9); DPP exchange (R13);
// all 8 x-steps pre-staged, ONE barrier/step (R12); halo-8 recompute (R9).
// R14: software pipeline (ping-pong acc, wave-group stagger 0/4).
// R15: rcp-fusion (7 trans/element), bias in spare x k-slot, zacc seed.
// R16: latency attack — (a) s_setprio(1) around h-MFMA cluster (T5),
// (b) pre-barrier x-MFMA hoist, (c) batched trans in epilogue.
// R17: REVERT launch_bounds to (512,2). R16's (512,4) forced VGPR 124->64;
// everything spilled to scratch (FETCH 16->330 MB, 2x time). Occupancy here
// is LDS-limited (55.8KB -> 2 blocks/CU); never squeeze the allocator.
// ---------------------------------------------------------------------------
__global__ __launch_bounds__(512, 2)
void lstm_kernel(const float* __restrict__ x, const f16* __restrict__ wpack,
                 f16* __restrict__ h_glob, float* __restrict__ c_glob, int phase)
{
    __shared__ __align__(16) f16 hlds[2][HROWS * 64];
    __shared__ __align__(16) f16 xt[8 * WCMP * 8];

    const int blk  = blockIdx.x;
    const int b    = blk >> 5;
    const int tau  = blk & 31;
    const int n0   = tau * WOUT;
    const int tid  = threadIdx.x;
    const int lane = tid & 63;
    const int wave = tid >> 6;             // 0..7
    const int m    = lane & 15;
    const int kg   = lane >> 4;
    const int gh   = m >> 3;               // gate half of this lane's column
    const int hid  = wave * 8 + (m & 7);
    const bool lowm = (m < 8);
    const bool edge = (tau == 0) || (tau == NTIL - 1);
    const int s0   = phase * 8;

    // B fragments, gate-packed: 14 half8 = 56 VGPR, resident all 8 steps.
    half8 bf[7][2];
#pragma unroll
    for (int kt = 0; kt < 7; ++kt)
#pragma unroll
        for (int q = 0; q < 2; ++q)
            bf[kt][q] = *(const half8*)(wpack + (size_t)((q * 2 + gh) * 64 + hid) * KPK + kt * 32 + kg * 8);

    const floatx4 zacc = {0.0f, 0.0f, 0.0f, 0.0f};   // persistent MFMA C seed

    float creg[NMS * 2];

    // ---- one-time staging: all 8 steps of x (slot3 = 1.0 pairs with bias) ----
    for (int i = tid; i < 8 * WCMP; i += 512) {
        int ss = i / WCMP, r = i - ss * WCMP;
        const float* xb = x + ((size_t)b * TSN + s0 + ss) * NNP;
        int p = n0 - HALO + r;
        float v0 = (p - 1 >= 0 && p - 1 < NNP) ? xb[p - 1] : 0.0f;
        float v1 = (p >= 0 && p < NNP) ? xb[p] : 0.0f;
        float v2 = (p + 1 >= 0 && p + 1 < NNP) ? xb[p + 1] : 0.0f;
        unsigned* q = (unsigned*)(xt + (size_t)i * 8);
        q[0] = f16pair(v0, v1);
        q[1] = f16pair(v2, 1.0f);
        q[2] = 0u; q[3] = 0u;
    }

    if (phase == 0) {
#pragma unroll
        for (int i = 0; i < NMS * 2; ++i) creg[i] = 0.0f;
        for (int i = tid; i < HROWS * 64; i += 512) { hlds[0][i] = (f16)0; hlds[1][i] = (f16)0; }
    } else {
        // seed h(8) window from global (rr <-> pos n0-HALO-1+rr), OOB -> 0
        for (int i = tid; i < HROWS * 8; i += 512) {
            int rr = i >> 3, c = i & 7;
            int pos = n0 - HALO - 1 + rr;
            half8 v = {};
            if (pos >= 0 && pos < NNP)
                v = *(const half8*)(h_glob + ((size_t)b * NNP + pos) * HID + c * 8);
            *(half8*)(hlds[0] + hadr(rr, c)) = v;
        }
        // hlds[1]: only halo rows 0 / HROWS-1 are read before being written
        for (int i = tid; i < 2 * 64; i += 512) {
            int rr = (i >= 64) ? (HROWS - 1) : 0;
            hlds[1][rr * 64 + (i & 63)] = (f16)0;
        }
#pragma unroll
        for (int ms = 0; ms < NMS; ++ms)
#pragma unroll
            for (int j = 0; j < 2; ++j) {
                int r   = lowm ? j : 2 + j;
                int pos = n0 - HALO + ms * 16 + kg * 4 + r;
                creg[ms * 2 + j] = (pos >= 0 && pos < NNP)
                    ? c_glob[((size_t)b * NNP + pos) * HID + hid] : 0.0f;
            }
    }

    __syncthreads();   // staging/seed writes vs first pre-barrier xt reads

#pragma unroll 1
    for (int s = s0; s < s0 + 8; ++s) {
        const f16* hrd = hlds[s & 1];
        f16*       hwr = hlds[(s & 1) ^ 1];
        const f16* xts = xt + (size_t)(s - s0) * WCMP * 8;

        floatx4 accA[2], accB[2];
#define MFX(MS, A) do_mfx<MS>(xts, bf, zacc, A, m)
#define MFH(MS, A) do_mfh<MS>(hrd, bf, A, m, kg)
#define MFF(MS, A) do { MFX(MS, A); MFH(MS, A); } while (0)
#define EP(MS, A)  do_epi<MS>(hwr, A, creg, m, kg, wave, lowm, edge, n0)
        // pre-barrier: x-part of the first two tiles (reads only xt, which is
        // written once before the loop — barrier-independent work)
        if (wave < 4) { MFX(0, accA); MFX(1, accB); }
        else          { MFX(4, accA); MFX(5, accB); }

        __syncthreads();   // step s's h reads vs step s-1's h writes

        if (wave < 4) {
            MFH(0, accA);
            MFH(1, accB); EP(0, accA);
            MFF(2, accA); EP(1, accB);
            MFF(3, accB); EP(2, accA);
            MFF(4, accA); EP(3, accB);
            MFF(5, accB); EP(4, accA);
            MFF(6, accA); EP(5, accB);
            MFF(7, accB); EP(6, accA);
            MFF(8, accA); EP(7, accB);
            EP(8, accA);
        } else {
            MFH(4, accA);
            MFH(5, accB); EP(4, accA);
            MFF(6, accA); EP(5, accB);
            MFF(7, accB); EP(6, accA);
            MFF(8, accA); EP(7, accB);
            MFF(0, accB); EP(8, accA);
            MFF(1, accA); EP(0, accB);
            MFF(2, accB); EP(1, accA);
            MFF(3, accA); EP(2, accB);
            EP(3, accA);
        }
#undef MFX
#undef MFH
#undef MFF
#undef EP
    }
    __syncthreads();   // last step's hwr (= hlds[0]) complete

    // h(s0+8) is in hlds[0] (last step is odd); valid rows rr = row+HALO+1.
    for (int i = tid; i < WOUT * 8; i += 512) {
        int row = i >> 3, c = i & 7;
        half8 v = *(const half8*)(hlds[0] + hadr(row + HALO + 1, c));
        *(half8*)(h_glob + ((size_t)b * NNP + n0 + row) * HID + c * 8) = v;
    }
    if (phase == 0) {
        // persist c(8) for valid rows
#pragma unroll
        for (int ms = 0; ms < NMS; ++ms)
#pragma unroll
            for (int j = 0; j < 2; ++j) {
                int r   = lowm ? j : 2 + j;
                int rit = ms * 16 + kg * 4 + r;
                int pos = n0 - HALO + rit;
                if (rit >= HALO && rit < HALO + WOUT && pos >= 0 && pos < NNP)
                    c_glob[((size_t)b * NNP + pos) * HID + hid] = creg[ms * 2 + j];
            }
    }
}

// ---------------------------------------------------------------------------
// fc: out[b,t,n] = sum_hid h[b][n][hid]*fc_w[hid] + fc_b, broadcast over t
// ---------------------------------------------------------------------------
__global__ void fc_kernel(const f16* __restrict__ h, const float* __restrict__ fc_w,
                          const float* __restrict__ fc_b, float* __restrict__ out) {
    int idx = blockIdx.x * 256 + threadIdx.x;      // b*NNP + n
    const half8* hp = (const half8*)(h + (size_t)idx * HID);
    float s = 0.0f;
#pragma unroll
    for (int q = 0; q < 8; ++q) {
        half8 v = hp[q];
#pragma unroll
        for (int e = 0; e < 8; ++e) s += (float)v[e] * fc_w[q * 8 + e];
    }
    s += fc_b[0];
    int b = idx >> 12, n = idx & (NNP - 1);
#pragma unroll
    for (int t = 0; t < TSN; ++t) out[((size_t)b * TSN + t) * NNP + n] = s;
}

extern "C" void kernel_launch(void* const* d_in, const int* in_sizes, int n_in,
                              void* d_out, int out_size, void* d_ws, size_t ws_size,
                              hipStream_t stream) {
    const float* x      = (const float*)d_in[0];
    const float* conv_w = (const float*)d_in[1];
    const float* conv_b = (const float*)d_in[2];
    const float* fc_w   = (const float*)d_in[3];
    const float* fc_b   = (const float*)d_in[4];
    float* out = (float*)d_out;

    char* ws = (char*)d_ws;
    const size_t hbytes = (size_t)BB * NNP * HID * sizeof(f16);     // 8.39 MB
    f16*   wpack  = (f16*)ws;                                       // 112 KiB
    f16*   h_glob = (f16*)(ws + 131072);
    float* c_glob = (float*)(ws + 131072 + hbytes);                 // 16.8 MB

    pack_w_kernel<<<(4 * 64 * KPK + 255) / 256, 256, 0, stream>>>(conv_w, conv_b, wpack);
    lstm_kernel<<<BB * NTIL, 512, 0, stream>>>(x, wpack, h_glob, c_glob, 0);
    lstm_kernel<<<BB * NTIL, 512, 0, stream>>>(x, wpack, h_glob, c_glob, 1);
    fc_kernel<<<BB * NNP / 256, 256, 0, stream>>>(h_glob, fc_w, fc_b, out);
}

// Round 4
// 249.819 us; speedup vs baseline: 1.9700x; 1.0191x over previous
//
#include <hip/hip_runtime.h>

typedef _Float16 f16;
typedef __attribute__((ext_vector_type(8))) _Float16 half8;
typedef __attribute__((ext_vector_type(4))) float floatx4;

#define BB    16
#define TSN   16
#define NNP   4096
#define HID   64
#define KPK   224     // 6 k-tiles of 32 (h taps) + 1 k-tile (x taps + bias)
#define WOUT  128     // valid output positions per block
#define HALO  16      // time-halo for a single 16-step launch (R18)
#define WCMP  160     // computed rows per step = WOUT + 2*HALO (10 m-tiles)
#define HROWS 162     // h-buffer rows = WCMP + 2 (conv halo)
#define NMS   10
#define NTIL  32

#define LOG2E 1.44269504088896340736f

// LDS h layout: row stride 64 f16 (128 B == 0 mod 32 banks), 16B chunk
// XOR-swizzled by row (phys_chunk = chunk ^ (row&7)) -> b128 reads balanced,
// dword epilogue writes conflict-light. [verified R5: conflicts 8.3M -> 229K]
__device__ __forceinline__ int hadr(int rr, int c) {   // f16 index
    return rr * 64 + ((c ^ (rr & 7)) << 3);
}
__device__ __forceinline__ unsigned f16pair(float a, float b) {
    union { f16 h; unsigned short u; } ua, ub;
    ua.h = (f16)a; ub.h = (f16)b;
    return (unsigned)ua.u | ((unsigned)ub.u << 16);
}
// one-instruction f32x2 -> f16x2 pack (v_cvt_pkrtz_f16_f32).
// NOTE: builtin returns __fp16-vector, not _Float16-vector (R14 compile fix).
__device__ __forceinline__ unsigned pkrtz(float a, float b) {
    typedef __fp16 h2v __attribute__((ext_vector_type(2)));
    h2v r = __builtin_amdgcn_cvt_pkrtz(a, b);
    union { h2v h; unsigned u; } cv; cv.h = r; return cv.u;
}

// Raw-rate transcendentals (no -ffast-math in harness). ~1 ulp each.
__device__ __forceinline__ float fast_exp2(float x) {
#if __has_builtin(__builtin_amdgcn_exp2f)
    return __builtin_amdgcn_exp2f(x);
#else
    return exp2f(x);
#endif
}
__device__ __forceinline__ float fast_rcp(float x) {
#if __has_builtin(__builtin_amdgcn_rcpf)
    return __builtin_amdgcn_rcpf(x);
#else
    return 1.0f / x;
#endif
}

// Lane exchanges via DPP (VALU) instead of ds_swizzle (DS pipe).
__device__ __forceinline__ float dpp_xor8(float v) {
    return __int_as_float(__builtin_amdgcn_mov_dpp(__float_as_int(v), 0x128, 0xF, 0xF, true));
}
__device__ __forceinline__ float dpp_xor1(float v) {
    return __int_as_float(__builtin_amdgcn_mov_dpp(__float_as_int(v), 0xB1, 0xF, 0xF, true));
}

// ---------------------------------------------------------------------------
// Pack conv_w (OIHW 256x65x3x3, only kw=1 live) -> f16 wpack[oc][k]:
//   k = kt*32+c;  kt<6: tap=kt>>1, ch j=(kt&1)*32+c;  kt=6: c<3 -> x tap c,
//   c==3 -> bias (paired with constant 1.0 in the x k-slot; R15).
// Gate pre-scale folded in: i/f/o by -log2e, g by 2*log2e.
// ---------------------------------------------------------------------------
__global__ void pack_w_kernel(const float* __restrict__ conv_w,
                              const float* __restrict__ conv_b,
                              f16* __restrict__ wpack) {
    int idx = blockIdx.x * 256 + threadIdx.x;
    if (idx >= 4 * 64 * KPK) return;
    int k  = idx % KPK;
    int oc = idx / KPK;
    int kt = k >> 5, c = k & 31;
    float w = 0.0f;
    if (kt < 6) {
        int tap = kt >> 1;
        int j   = (kt & 1) * 32 + c;
        w = conv_w[((oc * 65 + 1 + j) * 3 + tap) * 3 + 1];
    } else if (c < 3) {
        w = conv_w[((oc * 65 + 0) * 3 + c) * 3 + 1];
    } else if (c == 3) {
        w = conv_b[oc];                       // bias folded into MFMA (R15)
    }
    float scale = (oc >= 192) ? (2.0f * LOG2E) : (-LOG2E);
    wpack[oc * KPK + k] = (f16)(w * scale);
}

// ---------------------------------------------------------------------------
// x-part MFMA: reads only the step's pre-staged xt, seeds from zacc
// (bias folded via the 1.0 x-slot).
// ---------------------------------------------------------------------------
template <int MS>
__device__ __forceinline__ void do_mfx(
    const f16* __restrict__ xts, const half8 (&bf)[7][2],
    const floatx4& zacc, floatx4 (&acc)[2], int m)
{
    const int ar = MS * 16 + m;
    half8 a = *(const half8*)(xts + ar * 8);
    acc[0] = __builtin_amdgcn_mfma_f32_16x16x32_f16(a, bf[6][0], zacc, 0, 0, 0);
    acc[1] = __builtin_amdgcn_mfma_f32_16x16x32_f16(a, bf[6][1], zacc, 0, 0, 0);
}

// h-part: 12 MFMA cluster wrapped in s_setprio(1) (T5).
template <int MS>
__device__ __forceinline__ void do_mfh(
    const f16* __restrict__ hrd, const half8 (&bf)[7][2],
    floatx4 (&acc)[2], int m, int kg)
{
    const int ar = MS * 16 + m;
    __builtin_amdgcn_s_setprio(1);
#pragma unroll
    for (int kt = 0; kt < 6; ++kt) {
        half8 a = *(const half8*)(hrd + hadr(ar + (kt >> 1), (kt & 1) * 4 + kg));
        acc[0] = __builtin_amdgcn_mfma_f32_16x16x32_f16(a, bf[kt][0], acc[0], 0, 0, 0);
        acc[1] = __builtin_amdgcn_mfma_f32_16x16x32_f16(a, bf[kt][1], acc[1], 0, 0, 0);
    }
    __builtin_amdgcn_s_setprio(0);
}

// ---------------------------------------------------------------------------
// Single-tile epilogue: gate exchange (DPP), LSTM pointwise, h write.
// R15: rcp-fusion — 7 trans ops per element.
// R16: batched trans — 8 independent v_exp issue before dependent algebra.
// ---------------------------------------------------------------------------
template <int MS>
__device__ __forceinline__ void do_epi(
    f16* __restrict__ hwr, floatx4 (&acc)[2], float (&creg)[NMS * 2],
    int m, int kg, int wave, bool lowm, bool edge, int n0)
{
    float pg[2][2];
#pragma unroll
    for (int q = 0; q < 2; ++q)
#pragma unroll
        for (int j = 0; j < 2; ++j) {
            float send = lowm ? acc[q][2 + j] : acc[q][j];
            pg[q][j] = dpp_xor8(send);
        }

    // gate pre-activations, both elements: [j][i,f,o,g]
    float Y[2][4];
#pragma unroll
    for (int j = 0; j < 2; ++j) {
        Y[j][0] = lowm ? acc[0][j] : pg[0][j];
        Y[j][1] = lowm ? pg[0][j] : acc[0][2 + j];
        Y[j][2] = lowm ? acc[1][j] : pg[1][j];
        Y[j][3] = lowm ? pg[1][j] : acc[1][2 + j];
    }
    // 8 independent exps back-to-back (trans pipe fill)
    float E[2][4];
#pragma unroll
    for (int j = 0; j < 2; ++j)
#pragma unroll
        for (int g = 0; g < 4; ++g) E[j][g] = fast_exp2(Y[j][g]);

#pragma unroll
    for (int j = 0; j < 2; ++j) {
        int r  = lowm ? j : 2 + j;
        float Fi = 1.0f + E[j][0], Ff = 1.0f + E[j][1];
        float Fo = 1.0f + E[j][2], Fg = 1.0f + E[j][3];
        const int ridx = MS * 2 + j;
        float P  = Fi * Fg;
        float N  = fmaf(E[j][3] - 1.0f, Ff, creg[ridx] * P);
        float cn = N * fast_rcp(P * Ff);          // sig(f)*c + sig(i)*tanh(g)
        float Ec = fast_exp2(cn * (2.0f * LOG2E));
        float hnf = (Ec - 1.0f) * fast_rcp(Fo * (1.0f + Ec));  // sig(o)*tanh(cn)
        creg[ridx] = cn;
        int rit = MS * 16 + kg * 4 + r;        // compute-window row
        if (edge) {
            int pos = n0 - HALO + rit;
            if (pos < 0 || pos >= NNP) hnf = 0.0f;  // zero-pad semantics
        }
        float po = dpp_xor1(hnf);               // partner hid^1
        if (!(m & 1)) {                          // even lane packs dword
            int rr = rit + 1;
            ((unsigned*)hwr)[rr * 32 + ((wave ^ (rr & 7)) << 2) + ((m & 7) >> 1)] =
                pkrtz(hnf, po);
        }
    }
}

// ---------------------------------------------------------------------------
// ConvLSTM, ALL 16 steps in ONE launch (R18), 512 independent blocks.
// Block = 512 thr (8 waves). Gate-packed MFMA N-dim (R9); DPP exchange (R13);
// halo-16 recompute (R18: +11% MFMA work absorbs into latency stalls, buys:
// no c_glob round-trip (c stays in registers), no h_glob at all, no phase-1
// seed, one launch tail instead of two, fc fused into the drain).
// x pre-staged 8 steps at a time (LDS budget); restage at s==8 behind a
// double barrier. R14 ping-pong acc + wave-group stagger (tiles 0/5).
// R17 lesson: occupancy is VGPR-capped (4 waves/SIMD at 65-128 VGPR);
// keep launch_bounds(512,2) and stay under 128 VGPR.
// ---------------------------------------------------------------------------
__global__ __launch_bounds__(512, 2)
void lstm_kernel(const float* __restrict__ x, const f16* __restrict__ wpack,
                 const float* __restrict__ fc_w, const float* __restrict__ fc_b,
                 float* __restrict__ out)
{
    __shared__ __align__(16) f16 hlds[2][HROWS * 64];
    __shared__ __align__(16) f16 xt[8 * WCMP * 8];

    const int blk  = blockIdx.x;
    const int b    = blk >> 5;
    const int tau  = blk & 31;
    const int n0   = tau * WOUT;
    const int tid  = threadIdx.x;
    const int lane = tid & 63;
    const int wave = tid >> 6;             // 0..7
    const int m    = lane & 15;
    const int kg   = lane >> 4;
    const int gh   = m >> 3;               // gate half of this lane's column
    const int hid  = wave * 8 + (m & 7);
    const bool lowm = (m < 8);
    const bool edge = (tau == 0) || (tau == NTIL - 1);

    // B fragments, gate-packed: 14 half8 = 56 VGPR, resident all 16 steps.
    half8 bf[7][2];
#pragma unroll
    for (int kt = 0; kt < 7; ++kt)
#pragma unroll
        for (int q = 0; q < 2; ++q)
            bf[kt][q] = *(const half8*)(wpack + (size_t)((q * 2 + gh) * 64 + hid) * KPK + kt * 32 + kg * 8);

    const floatx4 zacc = {0.0f, 0.0f, 0.0f, 0.0f};   // persistent MFMA C seed

    float creg[NMS * 2];
#pragma unroll
    for (int i = 0; i < NMS * 2; ++i) creg[i] = 0.0f;

    // ---- stage 8 steps of x into xt (slot3 = 1.0 pairs with bias) ----
    auto stage_x = [&](int base) {
        for (int i = tid; i < 8 * WCMP; i += 512) {
            int ss = i / WCMP, r = i - ss * WCMP;
            const float* xb = x + ((size_t)b * TSN + base + ss) * NNP;
            int p = n0 - HALO + r;
            float v0 = (p - 1 >= 0 && p - 1 < NNP) ? xb[p - 1] : 0.0f;
            float v1 = (p >= 0 && p < NNP) ? xb[p] : 0.0f;
            float v2 = (p + 1 >= 0 && p + 1 < NNP) ? xb[p + 1] : 0.0f;
            unsigned* q = (unsigned*)(xt + (size_t)i * 8);
            q[0] = f16pair(v0, v1);
            q[1] = f16pair(v2, 1.0f);
            q[2] = 0u; q[3] = 0u;
        }
    };
    stage_x(0);

    // h(0) = 0; rows 0 / HROWS-1 of both buffers stay 0 forever (conv halo).
    for (int i = tid; i < HROWS * 64; i += 512) { hlds[0][i] = (f16)0; hlds[1][i] = (f16)0; }

#pragma unroll 1
    for (int s = 0; s < TSN; ++s) {
        if (s == 8) {
            __syncthreads();   // all step-7 xt reads complete before overwrite
            stage_x(8);
        }
        __syncthreads();   // step s's h reads vs step s-1's h writes (+ restage)

        const f16* hrd = hlds[s & 1];
        f16*       hwr = hlds[(s & 1) ^ 1];
        const f16* xts = xt + (size_t)(s & 7) * WCMP * 8;

        floatx4 accA[2], accB[2];
#define MFF(MS, A) do { do_mfx<MS>(xts, bf, zacc, A, m); do_mfh<MS>(hrd, bf, A, m, kg); } while (0)
#define EP(MS, A)  do_epi<MS>(hwr, A, creg, m, kg, wave, lowm, edge, n0)
        if (wave < 4) {
            MFF(0, accA);
            MFF(1, accB); EP(0, accA);
            MFF(2, accA); EP(1, accB);
            MFF(3, accB); EP(2, accA);
            MFF(4, accA); EP(3, accB);
            MFF(5, accB); EP(4, accA);
            MFF(6, accA); EP(5, accB);
            MFF(7, accB); EP(6, accA);
            MFF(8, accA); EP(7, accB);
            MFF(9, accB); EP(8, accA);
            EP(9, accB);
        } else {
            MFF(5, accA);
            MFF(6, accB); EP(5, accA);
            MFF(7, accA); EP(6, accB);
            MFF(8, accB); EP(7, accA);
            MFF(9, accA); EP(8, accB);
            MFF(0, accB); EP(9, accA);
            MFF(1, accA); EP(0, accB);
            MFF(2, accB); EP(1, accA);
            MFF(3, accA); EP(2, accB);
            MFF(4, accB); EP(3, accA);
            EP(4, accB);
        }
#undef MFF
#undef EP
    }
    __syncthreads();   // step-15 h writes complete (last write buffer = hlds[0])

    // ---- fused fc drain: out[b,t,n0+row] = dot(h[row,:], fc_w) + fc_b ----
    // 4 threads per row, 16 hid each; shuffle-reduce; LDS bounce for coalesced
    // stores (xt is dead — reuse as float scratch).
    {
        const int part = tid & 3, row = tid >> 2;      // row in [0,128)
        float fw[16];
#pragma unroll
        for (int e = 0; e < 16; ++e) fw[e] = fc_w[part * 16 + e];
        const int rr = row + HALO + 1;                 // valid window row
        float ssum = 0.0f;
#pragma unroll
        for (int cc = 0; cc < 2; ++cc) {
            half8 v = *(const half8*)(hlds[0] + hadr(rr, part * 2 + cc));
#pragma unroll
            for (int e = 0; e < 8; ++e) ssum += (float)v[e] * fw[cc * 8 + e];
        }
        ssum += __shfl_xor(ssum, 1);
        ssum += __shfl_xor(ssum, 2);
        float* srow = (float*)xt;
        if (part == 0) srow[row] = ssum + fc_b[0];
        __syncthreads();
        for (int i = tid; i < WOUT * TSN; i += 512) {
            int tt = i >> 7, r2 = i & (WOUT - 1);
            out[((size_t)b * TSN + tt) * NNP + n0 + r2] = srow[r2];
        }
    }
}

extern "C" void kernel_launch(void* const* d_in, const int* in_sizes, int n_in,
                              void* d_out, int out_size, void* d_ws, size_t ws_size,
                              hipStream_t stream) {
    const float* x      = (const float*)d_in[0];
    const float* conv_w = (const float*)d_in[1];
    const float* conv_b = (const float*)d_in[2];
    const float* fc_w   = (const float*)d_in[3];
    const float* fc_b   = (const float*)d_in[4];
    float* out = (float*)d_out;

    f16* wpack = (f16*)d_ws;                                        // 112 KiB

    pack_w_kernel<<<(4 * 64 * KPK + 255) / 256, 256, 0, stream>>>(conv_w, conv_b, wpack);
    lstm_kernel<<<BB * NTIL, 512, 0, stream>>>(x, wpack, fc_w, fc_b, out);
}